// Round 1
// baseline (98.273 us; speedup 1.0000x reference)
//
#include <hip/hip_runtime.h>
#include <hip/hip_bf16.h>
#include <stdint.h>

// ---------------------------------------------------------------------------
// coAttention: out = V_i + V_t + 0.5*V_c + 0.5*V_e
// where V = softmax_n( sum_k tanh(feat@W)[n,k]*wp[K+k] + bias[n] ) @ feat.
// The query half of tanh(concat([q,proj]))@wp is constant over n -> cancels
// in softmax -> the whole q0/q1/q2 chain (means, w_Vit_0/w_Vtce_1/w_Vice_2)
// is provably irrelevant. Four independent stages.
//
// Shapes: B=256, D=1024, K=256; N per stage: c=20, e=30, i=49, t=128.
// Flattened GEMM rows M = B*N: c=5120, e=7680, i=12544, t=32768 (all %128==0).
// ---------------------------------------------------------------------------

#define D_DIM 1024
#define K_OUT 256
#define BM 128
#define BK 64

typedef float f32x4 __attribute__((ext_vector_type(4)));
typedef short bf16x8 __attribute__((ext_vector_type(8)));
typedef unsigned short u16x8 __attribute__((ext_vector_type(8)));

static __device__ __forceinline__ unsigned short f2bf(float f) {
    return __builtin_bit_cast(unsigned short, __float2bfloat16(f));
}

// tanh(x) = 1 - 2/(exp(2x)+1); stable at +/-inf, ~1e-6 accurate.
static __device__ __forceinline__ float fast_tanh(float x) {
    float e = __expf(2.0f * x);
    return 1.0f - 2.0f / (e + 1.0f);
}

// ---------------------------------------------------------------------------
// Kernel 1: W (f32, [D][K] row-major) -> Wt (bf16, [K][D] row-major) per stage.
// grid (4 stages, 32 d-chunks), 256 threads.
// ---------------------------------------------------------------------------
__global__ __launch_bounds__(256) void convert_wt(
    const float* __restrict__ w_c, const float* __restrict__ w_e,
    const float* __restrict__ w_i, const float* __restrict__ w_t,
    unsigned short* __restrict__ wt_all)
{
    const float* wsel[4] = {w_c, w_e, w_i, w_t};
    const float* W = wsel[blockIdx.x];
    unsigned short* Wt = wt_all + (size_t)blockIdx.x * (K_OUT * D_DIM);
    const int d0 = blockIdx.y * 32;

    __shared__ float tile[32][K_OUT];   // 32 KB
    const int t = threadIdx.x;
    for (int i = 0; i < 32; ++i) {      // 32*256 elements / 256 threads
        int idx = t + i * 256;
        int dd = idx >> 8, n = idx & 255;
        tile[dd][n] = W[(size_t)(d0 + dd) * K_OUT + n];
    }
    __syncthreads();
    // thread t owns output row n = t
    unsigned short buf[32];
#pragma unroll
    for (int dd = 0; dd < 32; ++dd) buf[dd] = f2bf(tile[dd][t]);
#pragma unroll
    for (int i = 0; i < 4; ++i) {
        u16x8 v;
#pragma unroll
        for (int j = 0; j < 8; ++j) v[j] = buf[i * 8 + j];
        *reinterpret_cast<u16x8*>(&Wt[(size_t)t * D_DIM + d0 + i * 8]) = v;
    }
}

// ---------------------------------------------------------------------------
// Kernel 2: fused logits GEMM: s[m] = sum_k tanh( (feat@W)[m,k] ) * wp[256+k]
// All 4 stages in one launch. Tile BM=128 x 256 cols, BK=64, 512 threads
// (8 waves as 2Mx4N, wave tile 64x64). bf16 16x16x32 MFMA, f32 accum.
// LDS tiles XOR-swizzled (byte ^= (row&7)<<4) -> conflict-free ds_read_b128.
// ---------------------------------------------------------------------------
struct GemmStage {
    const float* feat;          // [M][1024] f32
    const unsigned short* wt;   // [256][1024] bf16
    const float* wp;            // [512] f32 (use [256..])
    float* s_out;               // [M]
    int blk_start;
};

__global__ __launch_bounds__(512) void logits_gemm(
    GemmStage g0, GemmStage g1, GemmStage g2, GemmStage g3)
{
    __shared__ __align__(16) unsigned char AsRaw[BM * 128];     // 128B/row (64 bf16)
    __shared__ __align__(16) unsigned char WsRaw[K_OUT * 128];
    __shared__ float wp2s[K_OUT];
    __shared__ float partial[BM][4];

    GemmStage st;
    const int bid = blockIdx.x;
    if (bid < g1.blk_start) st = g0;
    else if (bid < g2.blk_start) st = g1;
    else if (bid < g3.blk_start) st = g2;
    else st = g3;
    const int m0 = (bid - st.blk_start) * BM;

    const int t = threadIdx.x;
    if (t < K_OUT) wp2s[t] = st.wp[K_OUT + t];

    // staging assignments
    const int ar = t >> 2, ac2 = t & 3;   // A: row, 16-f32 segment
    const int wr = t >> 3, wc = t & 7;    // W: row (of 64), chunk
    // wave/frag coords
    const int wv = t >> 6, lane = t & 63;
    const int wm = wv >> 2, wn = wv & 3;
    const int q = lane >> 4, c16 = lane & 15;
    const int xa = c16 & 7;

    f32x4 acc[4][4];
#pragma unroll
    for (int i = 0; i < 4; ++i)
#pragma unroll
        for (int j = 0; j < 4; ++j) acc[i][j] = (f32x4){0.f, 0.f, 0.f, 0.f};

    const float* aptr = st.feat + (size_t)(m0 + ar) * D_DIM + ac2 * 16;
    const unsigned short* wptr = st.wt + (size_t)wr * D_DIM + wc * 8;
    const int ab0 = ar * 128 + ((((ac2 * 2)    ) ^ (ar & 7)) << 4);
    const int ab1 = ar * 128 + ((((ac2 * 2) + 1) ^ (ar & 7)) << 4);

#pragma unroll 1
    for (int kt = 0; kt < D_DIM / BK; ++kt) {
        const int d0 = kt * BK;
        __syncthreads();   // previous iteration's reads complete
        // ---- stage A: 16 f32 -> 16 bf16 -> 2x ds_write_b128 (swizzled) ----
        {
            f32x4 v0 = *reinterpret_cast<const f32x4*>(aptr + d0);
            f32x4 v1 = *reinterpret_cast<const f32x4*>(aptr + d0 + 4);
            f32x4 v2 = *reinterpret_cast<const f32x4*>(aptr + d0 + 8);
            f32x4 v3 = *reinterpret_cast<const f32x4*>(aptr + d0 + 12);
            u16x8 o0, o1;
#pragma unroll
            for (int j = 0; j < 4; ++j) {
                o0[j]     = f2bf(v0[j]); o0[4 + j] = f2bf(v1[j]);
                o1[j]     = f2bf(v2[j]); o1[4 + j] = f2bf(v3[j]);
            }
            *reinterpret_cast<u16x8*>(&AsRaw[ab0]) = o0;
            *reinterpret_cast<u16x8*>(&AsRaw[ab1]) = o1;
        }
        // ---- stage W: bf16 16B chunks, coalesced, swizzled write ----
#pragma unroll
        for (int i = 0; i < 4; ++i) {
            const int n = wr + i * 64;
            u16x8 v = *reinterpret_cast<const u16x8*>(wptr + (size_t)i * 64 * D_DIM + d0);
            const int bb = n * 128 + ((wc ^ (n & 7)) << 4);
            *reinterpret_cast<u16x8*>(&WsRaw[bb]) = v;
        }
        __syncthreads();
        // ---- compute: 2 K-substeps of 32, 16 MFMA each per wave ----
#pragma unroll
        for (int ks = 0; ks < 2; ++ks) {
            bf16x8 af[4], bfr[4];
            const int ck = (((ks * 4 + q) ^ xa)) << 4;
#pragma unroll
            for (int mt = 0; mt < 4; ++mt) {
                const int row = wm * 64 + mt * 16 + c16;
                af[mt] = *reinterpret_cast<const bf16x8*>(&AsRaw[row * 128 + ck]);
            }
#pragma unroll
            for (int nt = 0; nt < 4; ++nt) {
                const int row = wn * 64 + nt * 16 + c16;
                bfr[nt] = *reinterpret_cast<const bf16x8*>(&WsRaw[row * 128 + ck]);
            }
#pragma unroll
            for (int mt = 0; mt < 4; ++mt)
#pragma unroll
                for (int nt = 0; nt < 4; ++nt)
                    acc[mt][nt] = __builtin_amdgcn_mfma_f32_16x16x32_bf16(
                        af[mt], bfr[nt], acc[mt][nt], 0, 0, 0);
        }
    }

    // ---- epilogue: tanh(proj)*wp2, reduce 256 cols -> s_out[m] ----
    // acc[mt][nt][r] = proj[row = wm*64+mt*16+q*4+r][col = wn*64+nt*16+c16]
#pragma unroll
    for (int mt = 0; mt < 4; ++mt) {
#pragma unroll
        for (int r = 0; r < 4; ++r) {
            float v = 0.f;
#pragma unroll
            for (int nt = 0; nt < 4; ++nt) {
                const int col = wn * 64 + nt * 16 + c16;
                v += fast_tanh(acc[mt][nt][r]) * wp2s[col];
            }
            v += __shfl_xor(v, 1);
            v += __shfl_xor(v, 2);
            v += __shfl_xor(v, 4);
            v += __shfl_xor(v, 8);
            if (c16 == 0) partial[wm * 64 + mt * 16 + q * 4 + r][wn] = v;
        }
    }
    __syncthreads();
    if (t < BM)
        st.s_out[m0 + t] = partial[t][0] + partial[t][1] + partial[t][2] + partial[t][3];
}

// ---------------------------------------------------------------------------
// Kernel 3: per (b, stage): softmax over N logits (+bias), then V = P @ feat.
// grid (256, 4), 256 threads; thread handles 4 d's (f32x4).
// ---------------------------------------------------------------------------
struct PVStage {
    const float* s;       // [B*N]
    const float* bias;    // [N]
    const float* feat;    // [B*N][1024]
    float* v_out;         // [B][1024]
    int N;
};

__global__ __launch_bounds__(256) void softmax_pv(
    PVStage p0, PVStage p1, PVStage p2, PVStage p3)
{
    PVStage st = (blockIdx.y == 0) ? p0 : (blockIdx.y == 1) ? p1
               : (blockIdx.y == 2) ? p2 : p3;
    const int b = blockIdx.x, t = threadIdx.x;
    const int N = st.N;

    __shared__ float P[128];
    __shared__ float inv_s;

    if (t < N) P[t] = st.s[b * N + t] + st.bias[t];
    __syncthreads();
    if (t < 64) {
        float m = -3.4e38f;
        for (int n = t; n < N; n += 64) m = fmaxf(m, P[n]);
#pragma unroll
        for (int sh = 32; sh; sh >>= 1) m = fmaxf(m, __shfl_xor(m, sh));
        float ssum = 0.f;
        for (int n = t; n < N; n += 64) { float e = __expf(P[n] - m); P[n] = e; ssum += e; }
#pragma unroll
        for (int sh = 32; sh; sh >>= 1) ssum += __shfl_xor(ssum, sh);
        if (t == 0) inv_s = 1.0f / ssum;
    }
    __syncthreads();
    const float inv = inv_s;

    f32x4 accv = (f32x4){0.f, 0.f, 0.f, 0.f};
    const float* fb = st.feat + (size_t)b * N * D_DIM + t * 4;
    for (int n = 0; n < N; ++n) {
        f32x4 f = *reinterpret_cast<const f32x4*>(fb + (size_t)n * D_DIM);
        accv += (P[n] * inv) * f;
    }
    *reinterpret_cast<f32x4*>(&st.v_out[(size_t)b * D_DIM + t * 4]) = accv;
}

// ---------------------------------------------------------------------------
// Kernel 4: out = V_i + V_t + 0.5*V_c + 0.5*V_e
// ---------------------------------------------------------------------------
__global__ __launch_bounds__(256) void combine_out(
    const float* __restrict__ vc, const float* __restrict__ ve,
    const float* __restrict__ vi, const float* __restrict__ vt,
    float* __restrict__ out)
{
    const int i = (blockIdx.x * 256 + threadIdx.x) * 4;
    f32x4 a = *reinterpret_cast<const f32x4*>(vi + i);
    f32x4 bb = *reinterpret_cast<const f32x4*>(vt + i);
    f32x4 c = *reinterpret_cast<const f32x4*>(vc + i);
    f32x4 e = *reinterpret_cast<const f32x4*>(ve + i);
    *reinterpret_cast<f32x4*>(out + i) = a + bb + 0.5f * c + 0.5f * e;
}

// ---------------------------------------------------------------------------
extern "C" void kernel_launch(void* const* d_in, const int* in_sizes, int n_in,
                              void* d_out, int out_size, void* d_ws, size_t ws_size,
                              hipStream_t stream)
{
    const float* ifeature = (const float*)d_in[0];   // (256,49,1024)
    const float* tfeature = (const float*)d_in[1];   // (256,128,1024)
    const float* cfeature = (const float*)d_in[2];   // (256,20,1024)
    const float* efeature = (const float*)d_in[3];   // (256,30,1024)
    const float* w_Vc = (const float*)d_in[5];
    const float* w_Pc = (const float*)d_in[6];
    const float* b_Pc = (const float*)d_in[7];
    const float* w_Ve = (const float*)d_in[8];
    const float* w_Pe = (const float*)d_in[9];
    const float* b_Pe = (const float*)d_in[10];
    const float* w_Vi = (const float*)d_in[11];
    const float* w_Pi = (const float*)d_in[13];
    const float* b_Pi = (const float*)d_in[14];
    const float* w_Vt = (const float*)d_in[16];
    const float* w_Pt = (const float*)d_in[17];
    const float* b_Pt = (const float*)d_in[18];

    // workspace layout (needs ~7 MB)
    char* ws = (char*)d_ws;
    unsigned short* wt = (unsigned short*)ws;                 // 4 x 512KB bf16
    float* s_c = (float*)(ws + 2u * 1024 * 1024);             // 5120
    float* s_e = s_c + 5120;                                  // 7680
    float* s_i = s_e + 7680;                                  // 12544
    float* s_t = s_i + 12544;                                 // 32768
    float* v_c = (float*)(ws + 3u * 1024 * 1024);             // 4 x 1MB
    float* v_e = v_c + 256 * 1024;
    float* v_i = v_e + 256 * 1024;
    float* v_t = v_i + 256 * 1024;

    convert_wt<<<dim3(4, 32), 256, 0, stream>>>(w_Vc, w_Ve, w_Vi, w_Vt, wt);

    GemmStage g0{cfeature, wt + 0 * (K_OUT * D_DIM), w_Pc, s_c, 0};    // 5120/128  = 40 blocks
    GemmStage g1{efeature, wt + 1 * (K_OUT * D_DIM), w_Pe, s_e, 40};   // 7680/128  = 60
    GemmStage g2{ifeature, wt + 2 * (K_OUT * D_DIM), w_Pi, s_i, 100};  // 12544/128 = 98
    GemmStage g3{tfeature, wt + 3 * (K_OUT * D_DIM), w_Pt, s_t, 198};  // 32768/128 = 256
    logits_gemm<<<454, 512, 0, stream>>>(g0, g1, g2, g3);

    PVStage p0{s_c, b_Pc, cfeature, v_c, 20};
    PVStage p1{s_e, b_Pe, efeature, v_e, 30};
    PVStage p2{s_i, b_Pi, ifeature, v_i, 49};
    PVStage p3{s_t, b_Pt, tfeature, v_t, 128};
    softmax_pv<<<dim3(256, 4), 256, 0, stream>>>(p0, p1, p2, p3);

    combine_out<<<256, 256, 0, stream>>>(v_c, v_e, v_i, v_t, (float*)d_out);
}